// Round 8
// baseline (150.403 us; speedup 1.0000x reference)
//
#include <hip/hip_runtime.h>

// R15: DECOMPOSITION = dedicated prefetch streamer + R14 main kernel.
// Theory: 8 structural rewrites all pin at ~30us kernel while pulling only
// ~15MB at ~500GB/s effective; the HW sustains 6.3TB/s on the same data
// (harness fills, m13). Hypotheses left: H_cold (cold-miss service against
// the just-poisoned 256MiB L3 dominates; structured access never streams)
// vs H_compute (hidden ~25us of issue/LDS/atomic work). This round splits
// them: kernel 1 = maximal-TLP grid-stride int4 OR-reduce over ALL inputs
// (50.4MB, m13 pattern, ~8us, asm keep-alive, writes nothing) -> L3 warm;
// kernel 2 = R14 verbatim, all reads L3-hits.
//   score = fixed(111.7) + ~8 + k_warm.
// k_warm <= 12 -> H_cold confirmed + net win (~128-132); k_warm ~= 25+ ->
// H_compute confirmed at a bounded cost, memory question closed.

#define BDIM 64

__global__ __launch_bounds__(256)
void prefetch_kernel(const int4* __restrict__ p0, int n0,
                     const int4* __restrict__ p1, int n1,
                     const int4* __restrict__ p2, int n2,
                     const int4* __restrict__ p3, int n3,
                     const int4* __restrict__ p4, int n4,
                     const int4* __restrict__ p5, int n5)
{
    int sx = 0, sy = 0, sz = 0, sw = 0;
    const int stride = gridDim.x * 256;
    const int t0 = blockIdx.x * 256 + threadIdx.x;
    for (int i = t0; i < n0; i += stride) { int4 v = p0[i]; sx |= v.x; sy |= v.y; sz |= v.z; sw |= v.w; }
    for (int i = t0; i < n1; i += stride) { int4 v = p1[i]; sx |= v.x; sy |= v.y; sz |= v.z; sw |= v.w; }
    for (int i = t0; i < n2; i += stride) { int4 v = p2[i]; sx |= v.x; sy |= v.y; sz |= v.z; sw |= v.w; }
    for (int i = t0; i < n3; i += stride) { int4 v = p3[i]; sx |= v.x; sy |= v.y; sz |= v.z; sw |= v.w; }
    for (int i = t0; i < n4; i += stride) { int4 v = p4[i]; sx |= v.x; sy |= v.y; sz |= v.z; sw |= v.w; }
    for (int i = t0; i < n5; i += stride) { int4 v = p5[i]; sx |= v.x; sy |= v.y; sz |= v.z; sw |= v.w; }
    asm volatile("" :: "v"(sx), "v"(sy), "v"(sz), "v"(sw));   // keep loads live
}

__device__ __forceinline__ void gld16(const void* g, void* l) {
    __builtin_amdgcn_global_load_lds((__attribute__((address_space(1))) void*)g,
                                     (__attribute__((address_space(3))) void*)l,
                                     16, 0, 0);
}

__global__ __launch_bounds__(BDIM)
void mlpreg_kernel(const float* __restrict__ cont_p,
                   const float* __restrict__ cont_c,
                   const int* __restrict__ cat_p,
                   const int* __restrict__ cat_c,
                   const int* __restrict__ lengths,
                   const float* __restrict__ w_p1, const float* __restrict__ b_p1,
                   const float* __restrict__ w_p2, const float* __restrict__ b_p2,
                   const float* __restrict__ w_c1, const float* __restrict__ b_c1,
                   const float* __restrict__ w_c2, const float* __restrict__ b_c2,
                   const float* __restrict__ emb_g,  const float* __restrict__ emb_k,
                   const float* __restrict__ emb_pr, const float* __restrict__ emb_j,
                   const float* __restrict__ emb_r,  const float* __restrict__ emb_pl,
                   const float* __restrict__ emb_a,
                   const float* __restrict__ w_fc1, const float* __restrict__ b_fc1,
                   const float* __restrict__ w_fc2, const float* __restrict__ b_fc2,
                   float* __restrict__ out)
{
    constexpr int S = 256;
    // 10240 B total. Layout: [0..767] cont_p row | [768..1279] cont_c row |
    // [1280..2559] cat_p row (1280 ints). After consumption, aliased:
    // hist -> sBuf[0..95] (ints), sAcc -> sBuf[768..831], sPool -> sBuf[832..959].
    __shared__ __align__(16) float sBuf[2560];
    float* sPc  = sBuf;
    float* sCc  = sBuf + 768;
    int*   sKp  = (int*)(sBuf + 1280);
    int*   hist = (int*)sBuf;          // valid after B2
    float* sAcc = sBuf + 768;          // written at token-loop end
    float* sPool = sBuf + 832;         // written in tail

    const int lane = threadIdx.x;
    const int ch = lane & 31, h = lane >> 5;
    const int b = blockIdx.x;

    int L = lengths[b]; L = (L < 1) ? 1 : (L > S ? S : L);
    const float Lf = (float)L, invL = 1.0f / Lf;

    // ---- staging: global_load_lds 16B, wave-uniform chunk gating ----
    {
        const char* gp = (const char*)(cont_p + (size_t)b * 768);
        const char* gc = (const char*)(cont_c + (size_t)b * 512);
        const char* gk = (const char*)(cat_p + (size_t)b * 1280);
        const int lo = 16 * lane;
        const int bP = 12 * L, bC = 8 * L, bK = 20 * L;
        gld16(gp + lo, (char*)sPc);
        if (1024 < bP) gld16(gp + 1024 + lo, (char*)sPc + 1024);
        if (2048 < bP) gld16(gp + 2048 + lo, (char*)sPc + 2048);
        gld16(gc + lo, (char*)sCc);
        if (1024 < bC) gld16(gc + 1024 + lo, (char*)sCc + 1024);
        #pragma unroll
        for (int j = 0; j < 5; ++j)
            if (1024 * j < bK) gld16(gk + 1024 * j + lo, (char*)sKp + 1024 * j);
    }
    // cat_c: 2 predicated int4 register loads (consumed late; latency hidden)
    const int limc = 2 * L;
    const int4* KC = (const int4*)(cat_c + (size_t)b * 512);
    int4 qc0, qc1;
    const bool hc0 = (4 * lane < limc), hc1 = (256 + 4 * lane < limc);
    if (hc0) qc0 = KC[lane];
    if (hc1) qc1 = KC[lane + 64];

    // ---- small-weight register preloads (issue under staging latency) ----
    const float wp0 = w_p1[ch], wp1 = w_p1[32 + ch], wp2 = w_p1[64 + ch], bp = b_p1[ch];
    const float wc0 = w_c1[ch], wc1 = w_c1[32 + ch], bc = b_c1[ch];
    const float eg0 = emb_g[ch],  eg1 = emb_g[32 + ch];
    const float ek0 = emb_k[ch],  ek1 = emb_k[32 + ch];
    const float er0 = emb_pr[ch], er1 = emb_pr[32 + ch];
    const float bias2 = h ? b_c2[ch] : b_p2[ch];
    const float bf1 = b_fc1[lane];
    const float2 wf2 = *(const float2*)&w_fc2[2 * lane];
    const float bq0 = b_fc2[0], bq1 = b_fc2[1];

    __syncthreads();   // B1: vmcnt drain -> all staged data in LDS

    // ---- token relu-MLP: contiguous half-wave split of 4-token groups ----
    float aP = 0.f, aC = 0.f;
    {
        const int gf = L >> 2;            // full 4-token groups
        const int gh = (gf + 1) >> 1;     // h=0 takes [0,gh), h=1 takes [gh,gf)
        const float4* tp4 = (const float4*)sPc;
        const float4* tc4 = (const float4*)sCc;
        #pragma unroll 4
        for (int i = 0; i < gh; ++i) {
            const int g = h ? gh + i : i;
            if (g < gf) {
                float4 a  = tp4[3 * g], bb = tp4[3 * g + 1], cc = tp4[3 * g + 2];
                float4 d  = tc4[2 * g], ee = tc4[2 * g + 1];
                float p0 = fmaxf(fmaf(a.x,  wp0, fmaf(a.y,  wp1, fmaf(a.z,  wp2, bp))), 0.f);
                float p1 = fmaxf(fmaf(a.w,  wp0, fmaf(bb.x, wp1, fmaf(bb.y, wp2, bp))), 0.f);
                float p2 = fmaxf(fmaf(bb.z, wp0, fmaf(bb.w, wp1, fmaf(cc.x, wp2, bp))), 0.f);
                float p3 = fmaxf(fmaf(cc.y, wp0, fmaf(cc.z, wp1, fmaf(cc.w, wp2, bp))), 0.f);
                aP += (p0 + p1) + (p2 + p3);
                float q0 = fmaxf(fmaf(d.x,  wc0, fmaf(d.y,  wc1, bc)), 0.f);
                float q1 = fmaxf(fmaf(d.z,  wc0, fmaf(d.w,  wc1, bc)), 0.f);
                float q2 = fmaxf(fmaf(ee.x, wc0, fmaf(ee.y, wc1, bc)), 0.f);
                float q3 = fmaxf(fmaf(ee.z, wc0, fmaf(ee.w, wc1, bc)), 0.f);
                aC += (q0 + q1) + (q2 + q3);
            }
        }
        const int rem = L & 3;
        if (h == 0 && rem) {
            const float* tp = sPc + 12 * gf;
            const float* tc = sCc + 8 * gf;
            for (int r = 0; r < rem; ++r) {
                aP += fmaxf(fmaf(tp[3*r], wp0, fmaf(tp[3*r+1], wp1, fmaf(tp[3*r+2], wp2, bp))), 0.f);
                aC += fmaxf(fmaf(tc[2*r], wc0, fmaf(tc[2*r+1], wc1, bc)), 0.f);
            }
        }
        aP += __shfl_xor(aP, 32);
        aC += __shfl_xor(aC, 32);
        sAcc[lane] = (h ? aC : aP) * invL;   // aliases sCc start: reads done
    }
    __syncthreads();   // B2: fence -> hist may now overwrite cont_p region

    // ---- hist zero (aliased over consumed cont_p) ----
    hist[lane] = 0;
    if (lane < 32) hist[64 + lane] = 0;

    // ---- cat_p from LDS: per-lane int4, mod-5 field attribution ----
    int sg = 0, sk = 0, sp = 0;
    {
        const int limp = 5 * L;
        const int m0 = (lane << 2) % 5;
        #pragma unroll
        for (int j = 0; j < 5; ++j) {
            if (256 * j < limp) {
                int4 v4 = ((const int4*)sKp)[lane + 64 * j];
                const int base = 4 * lane + 256 * j;
                int mj = m0 + j; if (mj >= 5) mj -= 5;
                const int v[4] = {v4.x, v4.y, v4.z, v4.w};
                #pragma unroll
                for (int c = 0; c < 4; ++c) {
                    int f = mj + c; if (f >= 5) f -= 5;
                    const bool val = (base + c) < limp;
                    const int vv = v[c];
                    sg += (val && f == 0) ? vv : 0;
                    sk += (val && f == 1) ? vv : 0;
                    sp += (val && f == 2) ? vv : 0;
                    if (val && f >= 3) atomicAdd(&hist[(f == 4 ? 11 : 0) + vv], 1);
                }
            }
        }
        // cat_c from registers: even elem -> place, odd -> add
        if (hc0) {
            atomicAdd(&hist[45 + qc0.x], 1);
            if (4 * lane + 1 < limc) atomicAdd(&hist[64 + qc0.y], 1);
            if (4 * lane + 2 < limc) atomicAdd(&hist[45 + qc0.z], 1);
            if (4 * lane + 3 < limc) atomicAdd(&hist[64 + qc0.w], 1);
        }
        if (hc1) {
            atomicAdd(&hist[45 + qc1.x], 1);
            if (257 + 4 * lane < limc) atomicAdd(&hist[64 + qc1.y], 1);
            if (258 + 4 * lane < limc) atomicAdd(&hist[45 + qc1.z], 1);
            if (259 + 4 * lane < limc) atomicAdd(&hist[64 + qc1.w], 1);
        }
    }
    #pragma unroll
    for (int d = 32; d; d >>= 1) {
        sg += __shfl_xor(sg, d); sk += __shfl_xor(sk, d); sp += __shfl_xor(sp, d);
    }

    // ---- tail: unified halves (h=0 p-side, h=1 c-side), single row ----
    float A;
    {
        float fg = (float)sg, fk = (float)sk, fp = (float)sp;
        A = fmaf(Lf - fg, eg0, fg * eg1) + fmaf(Lf - fk, ek0, fk * ek1)
          + fmaf(Lf - fp, er0, fp * er1);
        A = h ? 0.f : A;
    }
    {
        // h=0: job(11)+rep(34) over hist[0..44]; h=1: place(19)+add(31) over hist[45..94]
        const float* tA = h ? emb_pl : emb_j;
        const float* tB = h ? emb_a  : emb_r;
        const int nA = h ? 19 : 11;
        const int nT = h ? 50 : 45;
        const int hb = h ? 45 : 0;
        #pragma unroll 5
        for (int r = 0; r < nT; ++r) {
            const float* p = (r < nA) ? (tA + (r << 5)) : (tB + ((r - nA) << 5));
            A = fmaf((float)hist[hb + r], p[ch], A);
        }
        sPool[(h << 5) + ch] = A * (invL * (h ? 0.5f : 0.2f));
    }
    {
        // unified 32x32 second layer (global weights: proven neutral in R10)
        const float* W2 = h ? w_c2 : w_p2;
        const float* acc = sAcc + (h << 5);
        float v = bias2;
        #pragma unroll 8
        for (int k = 0; k < 32; ++k)
            v = fmaf(acc[k], W2[(k << 5) + ch], v);
        sPool[64 + (h << 5) + ch] = v;
    }

    // ---- fc1 (one output per lane) + fc2 butterfly ----
    {
        float x = bf1, y = 0.f;
        #pragma unroll 8
        for (int k = 0; k < 128; k += 2) {
            float w0 = w_fc1[(size_t)k * 64 + lane];
            float w1 = w_fc1[(size_t)(k + 1) * 64 + lane];
            float2 u = *(const float2*)&sPool[k];
            x = fmaf(u.x, w0, x); y = fmaf(u.y, w1, y);
        }
        float hv = fmaxf(x + y, 0.f);
        float q0 = hv * wf2.x, q1 = hv * wf2.y;
        #pragma unroll
        for (int d = 32; d; d >>= 1) {
            q0 += __shfl_xor(q0, d); q1 += __shfl_xor(q1, d);
        }
        if (lane == 0) {
            float2 o2;
            o2.x = fmaxf(q0 + bq0, 0.f);
            o2.y = fmaxf(q1 + bq1, 0.f);
            *(float2*)&out[(size_t)b * 2] = o2;   // 8B-aligned per-row store
        }
    }
}

extern "C" void kernel_launch(void* const* d_in, const int* in_sizes, int n_in,
                              void* d_out, int out_size, void* d_ws, size_t ws_size,
                              hipStream_t stream) {
    const float* cont_p = (const float*)d_in[0];
    const float* cont_c = (const float*)d_in[1];
    const int*   cat_p  = (const int*)d_in[2];
    const int*   cat_c  = (const int*)d_in[3];
    const int*   lens   = (const int*)d_in[4];
    const float* w_p1   = (const float*)d_in[5];
    const float* b_p1   = (const float*)d_in[6];
    const float* w_p2   = (const float*)d_in[7];
    const float* b_p2   = (const float*)d_in[8];
    const float* w_c1   = (const float*)d_in[9];
    const float* b_c1   = (const float*)d_in[10];
    const float* w_c2   = (const float*)d_in[11];
    const float* b_c2   = (const float*)d_in[12];
    const float* emb_g  = (const float*)d_in[13];
    const float* emb_k  = (const float*)d_in[14];
    const float* emb_pr = (const float*)d_in[15];
    const float* emb_j  = (const float*)d_in[16];
    const float* emb_r  = (const float*)d_in[17];
    const float* emb_pl = (const float*)d_in[18];
    const float* emb_a  = (const float*)d_in[19];
    const float* w_fc1  = (const float*)d_in[20];
    const float* b_fc1  = (const float*)d_in[21];
    const float* w_fc2  = (const float*)d_in[22];
    const float* b_fc2  = (const float*)d_in[23];
    float* out = (float*)d_out;

    // prefetch streamer: all 4 input arrays + w_fc1 + lengths = 50.4 MB
    hipLaunchKernelGGL(prefetch_kernel, dim3(2048), dim3(256), 0, stream,
                       (const int4*)cont_p, 786432,
                       (const int4*)cat_p,  1310720,
                       (const int4*)cont_c, 524288,
                       (const int4*)cat_c,  524288,
                       (const int4*)w_fc1,  2048,
                       (const int4*)lens,   1024);

    hipLaunchKernelGGL(mlpreg_kernel, dim3(4096), dim3(BDIM), 0, stream,
                       cont_p, cont_c, cat_p, cat_c, lens,
                       w_p1, b_p1, w_p2, b_p2, w_c1, b_c1, w_c2, b_c2,
                       emb_g, emb_k, emb_pr, emb_j, emb_r, emb_pl, emb_a,
                       w_fc1, b_fc1, w_fc2, b_fc2, out);
}